// Round 2
// baseline (13.610 us; speedup 1.0000x reference)
//
#include <hip/hip_runtime.h>
#include <hip/hip_bf16.h>

// Embedding via one-hot @ W.T  ==  gather of W columns.
// X: [B=2, S=2048] int32 indices in [0, 32000)
// W: [E=128, V=32000] float32 (nn.Linear weight layout)
// out[b,s,e] = W[e, X[b,s]]
//
// R1 analysis: direct column gather = 524288 scattered 4B loads, each its own
// 64B line (stride 128KB) -> ~33.5MB random-granule traffic, latency/queue
// bound at ~2.5 TB/s effective => 13.3us.
// R2 plan: per-call transpose W -> Wt[V][E] in d_ws (streaming, coalesced both
// sides via LDS tile), then gather reads 512B contiguous per token.

#define VOCAB 32000
#define EMBED 128
#define NTOK  4096          // 2 * 2048
#define TV    64            // vocab rows per transpose tile

// ---- Kernel 1: transpose W[E][V] -> Wt[V][E] ----
// 500 blocks x 256 threads; tile = 128e x 64v staged in LDS.
__global__ __launch_bounds__(256) void transpose_w_kernel(
        const float* __restrict__ W,
        float* __restrict__ Wt) {
    __shared__ float lds[TV][EMBED + 1];   // +1 pad: break bank alignment
    const int v0 = blockIdx.x * TV;
    const int t  = threadIdx.x;

    // Load phase: 128 rows(e) x 64 cols(v) = 2048 float4 along v.
    // fi = k*256+t; e = fi/16 (16 float4 per e-row), c = fi%16.
    // 16 consecutive lanes read 256B contiguous, 256B-aligned. Coalesced.
    #pragma unroll
    for (int k = 0; k < 8; ++k) {
        int fi = k * 256 + t;
        int e  = fi >> 4;
        int c  = fi & 15;
        float4 w = *reinterpret_cast<const float4*>(
            &W[(size_t)e * VOCAB + v0 + c * 4]);
        lds[c * 4 + 0][e] = w.x;
        lds[c * 4 + 1][e] = w.y;
        lds[c * 4 + 2][e] = w.z;
        lds[c * 4 + 3][e] = w.w;
    }
    __syncthreads();

    // Store phase: 64 rows(v) x 32 float4 along e.
    // fi = k*256+t; v = fi/32, ec = fi%32. Wave writes 2 consecutive v-rows
    // = 1024B contiguous. Coalesced.
    #pragma unroll
    for (int k = 0; k < 8; ++k) {
        int fi = k * 256 + t;
        int v  = fi >> 5;
        int ec = fi & 31;
        float4 o;
        o.x = lds[v][ec * 4 + 0];
        o.y = lds[v][ec * 4 + 1];
        o.z = lds[v][ec * 4 + 2];
        o.w = lds[v][ec * 4 + 3];
        *reinterpret_cast<float4*>(&Wt[(size_t)(v0 + v) * EMBED + ec * 4]) = o;
    }
}

// ---- Kernel 2: gather rows of Wt ----
// One 32-lane group per token; 512B contiguous read per token.
#define VEC 4
#define THREADS_PER_TOK (EMBED / VEC)   // 32

__global__ __launch_bounds__(256) void embed_gather_kernel(
        const int* __restrict__ X,
        const float* __restrict__ Wt,
        float* __restrict__ out) {
    int gid = blockIdx.x * blockDim.x + threadIdx.x;
    int tok = gid / THREADS_PER_TOK;
    int eg  = gid % THREADS_PER_TOK;
    if (tok >= NTOK) return;

    int idx = X[tok];
    int e0  = eg * VEC;

    float4 v = *reinterpret_cast<const float4*>(
        &Wt[(size_t)idx * EMBED + e0]);
    *reinterpret_cast<float4*>(&out[(size_t)tok * EMBED + e0]) = v;
}

extern "C" void kernel_launch(void* const* d_in, const int* in_sizes, int n_in,
                              void* d_out, int out_size, void* d_ws, size_t ws_size,
                              hipStream_t stream) {
    const int*   X = (const int*)d_in[0];
    const float* W = (const float*)d_in[1];
    float*     out = (float*)d_out;
    float*      Wt = (float*)d_ws;       // 32000*128*4 = 16.4 MB << ws_size

    transpose_w_kernel<<<VOCAB / TV, 256, 0, stream>>>(W, Wt);

    const int total_threads = NTOK * THREADS_PER_TOK;    // 131072
    const int block = 256;
    const int grid  = (total_threads + block - 1) / block;  // 512
    embed_gather_kernel<<<grid, block, 0, stream>>>(X, Wt, out);
}

// Round 3
// 9.529 us; speedup vs baseline: 1.4283x; 1.4283x over previous
//
#include <hip/hip_runtime.h>
#include <hip/hip_bf16.h>

// Embedding via one-hot @ W.T  ==  gather of W columns.
// X: [B=2, S=2048] int32 indices in [0, 32000)
// W: [E=128, V=32000] float32 (nn.Linear weight layout)
// out[b,s,e] = W[e, X[b,s]]
//
// R1/R2 post-mortem: both direct gather and transpose+gather land ~13.4us,
// bound by ~33.5MB of scattered 64B-line traffic served by L3 at ~2.5TB/s.
// Root cause: every XCD touches all 128 e-rows -> 14MB line footprint per
// XCD L2 (4MB) -> ~100% L2 miss. Also only 8 waves/CU.
//
// R3: XCD-sliced gather. blockIdx % 8 maps round-robin to XCDs (m09);
// give XCD k only e-slice [16k,16k+16) -> per-XCD W footprint = 16 rows
// x 128KB = 2MB, L2-resident across graph replays. One thread per output
// scalar: 2048 blocks x 256 threads = full occupancy (32 waves/CU).

#define VOCAB 32000
#define EMBED 128
#define NTOK  4096          // 2 * 2048
#define NXCD  8
#define ESLICE (EMBED / NXCD)        // 16 e-values per XCD slice
#define TOKCHUNK 16                  // tokens per block (16 tok x 16 e = 256 thr)
#define NCHUNK (NTOK / TOKCHUNK)     // 256 token chunks

__global__ __launch_bounds__(256) void embed_gather_xcd_kernel(
        const int* __restrict__ X,
        const float* __restrict__ W,
        float* __restrict__ out) {
    // Round-robin XCD assignment: consecutive blockIdx -> different XCDs.
    // slice = bid & 7 keeps each e-slice pinned to one XCD.
    const int slice = blockIdx.x & (NXCD - 1);
    const int chunk = blockIdx.x >> 3;

    const int tl = threadIdx.x & (ESLICE - 1);   // e within slice
    const int tt = threadIdx.x >> 4;             // token within chunk

    const int tok = chunk * TOKCHUNK + tt;
    const int e   = slice * ESLICE + tl;

    const int idx = X[tok];                      // 16-way broadcast, L1 hit

    // Scattered 4B read within this XCD's 2MB W slice (L2-resident).
    const float v = W[(size_t)e * VOCAB + idx];

    // 16 lanes write 64B contiguous per token; 4 chunks per wave.
    out[(size_t)tok * EMBED + e] = v;
}

extern "C" void kernel_launch(void* const* d_in, const int* in_sizes, int n_in,
                              void* d_out, int out_size, void* d_ws, size_t ws_size,
                              hipStream_t stream) {
    const int*   X = (const int*)d_in[0];
    const float* W = (const float*)d_in[1];
    float*     out = (float*)d_out;

    const int grid = NCHUNK * NXCD;   // 2048 blocks, one output scalar/thread
    embed_gather_xcd_kernel<<<grid, 256, 0, stream>>>(X, W, out);
}